// Round 1
// 80.469 us; speedup vs baseline: 1.0033x; 1.0033x over previous
//
#include <hip/hip_runtime.h>
#include <math.h>

#define N_SAMPLES 131072
#define N_EVENTS 128
#define N_ATOMS 32
#define ATOM_SIZE 512
#define LATENT 16
#define TIME_DIM 17
#define LAYERS 7

// dot of a 16-element f32 weight row with a broadcast x held in registers
__device__ __forceinline__ float dot16_bcast(const float* __restrict__ wr,
                                             const float xs[16]) {
    const float4* q = (const float4*)wr;
    float4 a = q[0], b = q[1], c = q[2], d = q[3];
    float s = 0.f;
    s += a.x * xs[0]  + a.y * xs[1]  + a.z * xs[2]  + a.w * xs[3];
    s += b.x * xs[4]  + b.y * xs[5]  + b.z * xs[6]  + b.w * xs[7];
    s += c.x * xs[8]  + c.y * xs[9]  + c.z * xs[10] + c.w * xs[11];
    s += d.x * xs[12] + d.y * xs[13] + d.z * xs[14] + d.w * xs[15];
    return s;
}

// One block per event, 512 threads (one output column per thread).
//
// Phase 1 (wave 0 only, ZERO block barriers): walk the 7-layer binary tree
// path for event b. x lives in registers of lanes 0..15 and is broadcast
// each layer via __shfl; lanes 16..49 accumulate the 34 time offsets in
// registers. Dirac position p comes from a __shfl_xor pairwise compare +
// __ballot (no serial thread-0 scan). Lanes 0..31 then compute the atom
// coefficients, lane 0 the amplitude.
//
// Phase 2 (all 512 threads): windowed atom column, block L2-norm reduce
// (shfl_xor within wave + 8-entry LDS combine, every thread folds the 8
// partials itself — saves a barrier), then atomicAdd scatter into
// out[p .. p+512) (out pre-zeroed by memset).
//
// Barriers per block: 16 (previous version) -> 2.
__global__ __launch_bounds__(512) void expand_scatter_kernel(
    const float* __restrict__ base_latent,
    const float* __restrict__ to_time_W,
    const float* __restrict__ split_W,
    const float* __restrict__ split_b,
    const float* __restrict__ atoms,
    const float* __restrict__ to_atoms_W,
    const float* __restrict__ to_atoms_b,
    const float* __restrict__ to_amp_W,
    const float* __restrict__ to_amp_b,
    float* __restrict__ out)   // [131072], pre-zeroed
{
    const int b = blockIdx.x;
    const int t = threadIdx.x;

    __shared__ float a32[N_ATOMS];
    __shared__ float s_amp;
    __shared__ float wred[8];
    __shared__ int s_p;

    if (t < 64) {
        const int l = t;
        float xv = (l < LATENT) ? base_latent[l] : 0.f;
        float tm = 0.f;
        float xs[16];

        for (int i = 0; i < LAYERS; ++i) {
            const int c = (b >> (6 - i)) & 1;
            // broadcast current x (lanes 0..15) to every lane, BEFORE update
#pragma unroll
            for (int j = 0; j < 16; ++j) xs[j] = __shfl(xv, j, 64);
            if (l < LATENT) {
                const int row = i * 32 + c * LATENT + l;
                xv = split_b[row] + dot16_bcast(split_W + row * LATENT, xs);
            } else if (l < LATENT + 2 * TIME_DIM) {
                const int row = i * 68 + c * (2 * TIME_DIM) + (l - LATENT);
                tm += dot16_bcast(to_time_W + row * LATENT, xs);
            }
        }

        // --- dirac position: lane 16+2d holds times[2d], 17+2d holds times[2d+1]
        const float other = __shfl_xor(tm, 1, 64);
        const bool timelane_even =
            (l >= LATENT) && (l < LATENT + 2 * TIME_DIM) && (((l - LATENT) & 1) == 0);
        const unsigned long long mask = __ballot(timelane_even && (other > tm));

        // --- final x broadcast for the head layers
#pragma unroll
        for (int j = 0; j < 16; ++j) xs[j] = __shfl(xv, j, 64);

        if (l < N_ATOMS)
            a32[l] = to_atoms_b[l] + dot16_bcast(to_atoms_W + l * LATENT, xs);

        if (l == 0) {
            int p = 0;
#pragma unroll
            for (int d = 0; d < TIME_DIM; ++d)
                if ((mask >> (LATENT + 2 * d)) & 1ull) p |= 1 << (16 - d);
            s_p = p;
            s_amp = to_amp_b[0] + dot16_bcast(to_amp_W, xs);
        }
    }
    __syncthreads();

    // --- windowed atom: one column per thread ---
    float acc = 0.f;
#pragma unroll
    for (int m = 0; m < N_ATOMS; ++m) acc += a32[m] * atoms[m * ATOM_SIZE + t];
    const float wnd = 0.54f - 0.46f * cosf((float)t * (float)(M_PI / 256.0));
    const float v = wnd * acc;

    // --- block reduce of sum-of-squares (8 waves) ---
    float ss = v * v;
#pragma unroll
    for (int off = 32; off > 0; off >>= 1) ss += __shfl_xor(ss, off, 64);
    if ((t & 63) == 0) wred[t >> 6] = ss;
    __syncthreads();

    float tot = 0.f;
#pragma unroll
    for (int w = 0; w < 8; ++w) tot += wred[w];
    const float scale = s_amp / (sqrtf(tot) + 1e-8f);

    // --- scatter into out[p .. p+512), clipped to N_SAMPLES ---
    const int k = s_p + t;
    if (k < N_SAMPLES) atomicAdd(out + k, v * scale);
}

extern "C" void kernel_launch(void* const* d_in, const int* in_sizes, int n_in,
                              void* d_out, int out_size, void* d_ws, size_t ws_size,
                              hipStream_t stream)
{
    const float* base_latent = (const float*)d_in[0];
    const float* to_time_W   = (const float*)d_in[1];
    const float* split_W     = (const float*)d_in[2];
    const float* split_b     = (const float*)d_in[3];
    const float* atoms       = (const float*)d_in[4];
    const float* to_atoms_W  = (const float*)d_in[5];
    const float* to_atoms_b  = (const float*)d_in[6];
    const float* to_amp_W    = (const float*)d_in[7];
    const float* to_amp_b    = (const float*)d_in[8];

    // d_out is poisoned 0xAA before every launch — zero it, then scatter-add.
    hipMemsetAsync(d_out, 0, (size_t)out_size * sizeof(float), stream);

    expand_scatter_kernel<<<N_EVENTS, 512, 0, stream>>>(
        base_latent, to_time_W, split_W, split_b, atoms,
        to_atoms_W, to_atoms_b, to_amp_W, to_amp_b, (float*)d_out);
}